// Round 3
// baseline (226.724 us; speedup 1.0000x reference)
//
#include <hip/hip_runtime.h>
#include <math.h>

#define BN   32
#define CN   256
#define HN   56
#define WN   56
#define HWN  (HN * WN)          // 3136
#define HW4  (HWN / 4)          // 784 float4 quads per spatial plane
#define CHWN (CN * HWN)         // 802816
#define NPOS (BN * HWN)         // 100352
#define NQ   (NPOS / 4)         // 25088 quads total
#define NTOT (BN * CHWN)        // 25690112

typedef float f32x4 __attribute__((ext_vector_type(4)));

// Kernel 1: channel-wise mean & max per spatial position.
//   - float4 over w (16B/lane loads)
//   - 8-way channel split across lane groups (lane>>3 = chunk, lane&7 = quad)
//   - butterfly __shfl_xor combine over lane bits 3..5
// 3136 waves (~12/CU), ~100KB/CU in flight vs ~9KB needed -> BW-bound.
// Regular (caching) loads on purpose: x must allocate in L3 so kernel 2's
// re-read of x is an Infinity-Cache hit, not HBM.
__global__ __launch_bounds__(256) void sa_reduce_kernel(const f32x4* __restrict__ x4,
                                                        f32x4* __restrict__ avg4,
                                                        f32x4* __restrict__ mx4) {
    int t    = blockIdx.x * 256 + threadIdx.x;
    int wave = t >> 6;
    int lane = t & 63;
    int q     = (wave << 3) | (lane & 7);   // quad index in [0, NQ)
    int chunk = lane >> 3;                  // 8 chunks x 32 channels
    if (q >= NQ) return;
    int b  = q / HW4;
    int s4 = q - b * HW4;
    const f32x4* xp = x4 + (size_t)b * (CHWN / 4) + (size_t)chunk * 32 * HW4 + s4;

    f32x4 sum = {0.0f, 0.0f, 0.0f, 0.0f};
    f32x4 m   = {-INFINITY, -INFINITY, -INFINITY, -INFINITY};
#pragma unroll 16
    for (int c = 0; c < 32; ++c) {
        f32x4 v = xp[(size_t)c * HW4];
        sum += v;
        m.x = fmaxf(m.x, v.x);
        m.y = fmaxf(m.y, v.y);
        m.z = fmaxf(m.z, v.z);
        m.w = fmaxf(m.w, v.w);
    }
#pragma unroll
    for (int off = 8; off < 64; off <<= 1) {
        sum.x += __shfl_xor(sum.x, off);
        sum.y += __shfl_xor(sum.y, off);
        sum.z += __shfl_xor(sum.z, off);
        sum.w += __shfl_xor(sum.w, off);
        m.x = fmaxf(m.x, __shfl_xor(m.x, off));
        m.y = fmaxf(m.y, __shfl_xor(m.y, off));
        m.z = fmaxf(m.z, __shfl_xor(m.z, off));
        m.w = fmaxf(m.w, __shfl_xor(m.w, off));
    }
    if (chunk == 0) {
        f32x4 a = sum * (1.0f / (float)CN);
        avg4[q] = a;
        mx4[q]  = m;
    }
}

// Kernel 2 (fused conv + sigmoid + multiply): one block per (b, h) row.
//   - stage the 7-row avg/mx halo (L2-resident, ~3KB) into LDS
//   - 56 threads compute the 7x7x2 conv + sigmoid -> att row in LDS
//   - all 256 threads stream x[b][:][h][:] (56KB), multiply by att, store out
// nt-load on x (dead after this kernel) + nt-store on out (never re-read):
// don't let the 103MB out stream evict the L3-resident copy of x.
__global__ __launch_bounds__(256) void sa_convmul_kernel(const f32x4* __restrict__ x4,
                                                         const float* __restrict__ avg,
                                                         const float* __restrict__ mx,
                                                         const float* __restrict__ cw,
                                                         f32x4* __restrict__ out4) {
    __shared__ __align__(16) float s_av[7][WN];
    __shared__ __align__(16) float s_mx[7][WN];
    __shared__ __align__(16) float s_att[WN];
    __shared__ float s_cw[98];

    int b = blockIdx.y;
    int h = blockIdx.x;
    int t = threadIdx.x;

    if (t < 98) s_cw[t] = cw[t];
    // halo rows: 7 rows x (14 avg quads + 14 mx quads) = 196 quad loads
    if (t < 196) {
        int kh = t / 28, r = t % 28;
        int hh = h + kh - 3;
        if (hh >= 0 && hh < HN) {
            const float* src = (r < 14 ? avg : mx) + (size_t)b * HWN + hh * WN + (r % 14) * 4;
            float* dst = (r < 14 ? &s_av[kh][0] : &s_mx[kh][0]) + (r % 14) * 4;
            *(f32x4*)dst = *(const f32x4*)src;
        }
    }
    __syncthreads();

    if (t < WN) {
        int w = t;
        float acc = 0.0f;
#pragma unroll
        for (int kh = 0; kh < 7; ++kh) {
            int hh = h + kh - 3;
            if (hh < 0 || hh >= HN) continue;
#pragma unroll
            for (int kw = 0; kw < 7; ++kw) {
                int ww = w + kw - 3;
                if (ww < 0 || ww >= WN) continue;
                acc = fmaf(s_cw[kh * 7 + kw],      s_av[kh][ww], acc);
                acc = fmaf(s_cw[49 + kh * 7 + kw], s_mx[kh][ww], acc);
            }
        }
        s_att[w] = 1.0f / (1.0f + expf(-acc));
    }
    __syncthreads();

    // multiply: 256 channels x 14 quads = 3584 quads, 14 per thread
    size_t plane = (size_t)b * (CHWN / 4) + (size_t)h * (WN / 4);
#pragma unroll 2
    for (int j = t; j < CN * (WN / 4); j += 256) {
        int c  = j / (WN / 4);
        int w4 = j - c * (WN / 4);
        size_t gi = plane + (size_t)c * HW4 + w4;
        f32x4 v = __builtin_nontemporal_load(x4 + gi);
        f32x4 a = *(const f32x4*)&s_att[w4 * 4];
        v *= a;
        __builtin_nontemporal_store(v, out4 + gi);
    }
}

extern "C" void kernel_launch(void* const* d_in, const int* in_sizes, int n_in,
                              void* d_out, int out_size, void* d_ws, size_t ws_size,
                              hipStream_t stream) {
    const float* x  = (const float*)d_in[0];
    const float* cw = (const float*)d_in[1];
    float* out = (float*)d_out;

    float* avg = (float*)d_ws;
    float* mx  = avg + NPOS;

    {
        int threads = 256;
        int blocks = (NQ * 8 + threads - 1) / threads;       // 784
        sa_reduce_kernel<<<blocks, threads, 0, stream>>>(
            (const f32x4*)x, (f32x4*)avg, (f32x4*)mx);
    }
    {
        dim3 grid(HN, BN);                                   // (56, 32) = 1792 blocks
        sa_convmul_kernel<<<grid, 256, 0, stream>>>(
            (const f32x4*)x, avg, mx, cw, (f32x4*)out);
    }
}

// Round 5
// 203.219 us; speedup vs baseline: 1.1157x; 1.1157x over previous
//
#include <hip/hip_runtime.h>
#include <math.h>

#define BN   32
#define CN   256
#define HN   56
#define WN   56
#define HWN  (HN * WN)          // 3136
#define HW4  (HWN / 4)          // 784 float4 quads per spatial plane
#define CHW4 (CN * HW4)         // 200704 quads per batch
#define CHWN (CN * HWN)         // 802816
#define NPOS (BN * HWN)         // 100352
#define NQ   (NPOS / 4)         // 25088 quads total

typedef float f32x4 __attribute__((ext_vector_type(4)));

// Kernel 1: channel-wise mean & max.
// 784 blocks x 512 threads. Block owns a 32-quad (512B) span of the output.
// The 8 waves split the 256 channels: wave w covers channels [w*32, w*32+32),
// two channels per wave-instruction (lane = 32*sub + quad). Every load
// instruction fetches 2 ALIGNED 512B-contiguous fragments (vs r2's 8
// scattered 128B fragments) -> better DRAM efficiency.
// Partials combined through LDS (16 partials per quad).
// Plain (caching) loads on purpose: x must allocate in L3 so kernel 3's
// re-read of x is an Infinity-Cache hit.
__global__ __launch_bounds__(512) void sa_reduce_kernel(const f32x4* __restrict__ x4,
                                                        f32x4* __restrict__ avg4,
                                                        f32x4* __restrict__ mx4) {
    __shared__ f32x4 s_sum[16][32];
    __shared__ f32x4 s_max[16][32];

    int t    = threadIdx.x;
    int lane = t & 63;
    int w    = t >> 6;            // wave 0..7
    int j    = lane & 31;         // quad within block's span
    int sub  = lane >> 5;         // channel parity within wave

    int q  = blockIdx.x * 32 + j; // global quad index, exact fit (784*32 == NQ)
    int b  = q / HW4;
    int s4 = q - b * HW4;
    const f32x4* xp = x4 + (size_t)b * CHW4 + (size_t)(w * 32 + sub) * HW4 + s4;

    f32x4 sum = {0.0f, 0.0f, 0.0f, 0.0f};
    f32x4 m   = {-INFINITY, -INFINITY, -INFINITY, -INFINITY};
#pragma unroll
    for (int k = 0; k < 16; ++k) {           // channels w*32 + sub + 2k
        f32x4 v = xp[(size_t)(2 * k) * HW4];
        sum += v;
        m.x = fmaxf(m.x, v.x);
        m.y = fmaxf(m.y, v.y);
        m.z = fmaxf(m.z, v.z);
        m.w = fmaxf(m.w, v.w);
    }
    s_sum[w * 2 + sub][j] = sum;
    s_max[w * 2 + sub][j] = m;
    __syncthreads();

    if (t < 32) {
        f32x4 sa = s_sum[0][t];
        f32x4 ma = s_max[0][t];
#pragma unroll
        for (int p = 1; p < 16; ++p) {
            sa += s_sum[p][t];
            f32x4 mp = s_max[p][t];
            ma.x = fmaxf(ma.x, mp.x);
            ma.y = fmaxf(ma.y, mp.y);
            ma.z = fmaxf(ma.z, mp.z);
            ma.w = fmaxf(ma.w, mp.w);
        }
        int qq = blockIdx.x * 32 + t;
        avg4[qq] = sa * (1.0f / (float)CN);
        mx4[qq]  = ma;
    }
}

// Kernel 2: 7x7 conv over the 2-channel (avg,max) map + sigmoid -> att map.
// Inputs 0.8 MB, L2/L3-resident; compute trivial (~4us).
__global__ __launch_bounds__(256) void sa_conv_kernel(const float* __restrict__ avg,
                                                      const float* __restrict__ mx,
                                                      const float* __restrict__ cw,
                                                      float* __restrict__ att) {
    int p = blockIdx.x * blockDim.x + threadIdx.x;
    if (p >= NPOS) return;
    int b = p / HWN;
    int s = p - b * HWN;
    int h = s / WN;
    int w = s - h * WN;
    const float* a0 = avg + b * HWN;
    const float* m0 = mx + b * HWN;
    float acc = 0.0f;
#pragma unroll
    for (int kh = 0; kh < 7; ++kh) {
        int hh = h + kh - 3;
        if (hh < 0 || hh >= HN) continue;
#pragma unroll
        for (int kw = 0; kw < 7; ++kw) {
            int ww = w + kw - 3;
            if (ww < 0 || ww >= WN) continue;
            int idx = hh * WN + ww;
            acc = fmaf(cw[kh * 7 + kw],      a0[idx], acc);
            acc = fmaf(cw[49 + kh * 7 + kw], m0[idx], acc);
        }
    }
    att[p] = 1.0f / (1.0f + expf(-acc));
}

// Kernel 3: out = x * att (broadcast over channels). Linear streaming:
// consecutive blocks/waves touch consecutive 1KB-aligned spans (no fragments,
// no partial cache lines). x via PLAIN load — probes/hits L3 where kernel 1
// left it resident (r3 showed nt paths only got partial hits). out via
// nt-store: never re-read, don't let it evict x from L3 mid-kernel.
__global__ __launch_bounds__(256) void sa_mul_kernel(const f32x4* __restrict__ x4,
                                                     const f32x4* __restrict__ att4,
                                                     f32x4* __restrict__ out4) {
    int b = blockIdx.y;
    int i = blockIdx.x * 256 + threadIdx.x;     // quad index within batch
    int sq = i % HW4;                           // spatial quad
    f32x4 a = att4[(size_t)b * HW4 + sq];       // L2-resident, reused 256x
    size_t gi = (size_t)b * CHW4 + i;
    f32x4 v = x4[gi];
    v *= a;
    __builtin_nontemporal_store(v, out4 + gi);
}

extern "C" void kernel_launch(void* const* d_in, const int* in_sizes, int n_in,
                              void* d_out, int out_size, void* d_ws, size_t ws_size,
                              hipStream_t stream) {
    const float* x  = (const float*)d_in[0];
    const float* cw = (const float*)d_in[1];
    float* out = (float*)d_out;

    float* avg = (float*)d_ws;
    float* mx  = avg + NPOS;
    float* att = mx + NPOS;

    {
        sa_reduce_kernel<<<NQ / 32, 512, 0, stream>>>(   // 784 blocks
            (const f32x4*)x, (f32x4*)avg, (f32x4*)mx);
    }
    {
        int blocks = (NPOS + 255) / 256;                 // 392
        sa_conv_kernel<<<blocks, 256, 0, stream>>>(avg, mx, cw, att);
    }
    {
        dim3 grid(CHW4 / 256, BN);                       // (784, 32)
        sa_mul_kernel<<<grid, 256, 0, stream>>>(
            (const f32x4*)x, (const f32x4*)att, (f32x4*)out);
    }
}